// Round 9
// baseline (375.266 us; speedup 1.0000x reference)
//
#include <hip/hip_runtime.h>
#include <stdint.h>

#define BATCH 16
#define CIN   32
#define HH    128
#define WW    128
#define BO    32
#define OCH   128   // 4*BO
#define NCH   16    // h-chunks (8 rows each)
#define DEPTH 64    // handoff ring depth (power of 2)

#define WLP   68    // padded weight row (64 + 4): banks spread 4 apart
#define PHP   36    // padded phs row (32 + 4)
#define GBP   (OCH + 4)

// ws: [0,4096) progress ints
//     [4096, +RINGSZ) tagged handoff ring
//     [4096+RINGSZ, +I2SSZ) i2s buffer (fp32)
#define RINGSZ ((size_t)BATCH * NCH * DEPTH * BO * 8)
#define I2SSZ  ((size_t)BATCH * HH * WW * OCH * 4)

// ================= K1: i2s GEMM  (i2s[b,row,t,o] = b2+b1 + sum_c W2*x_skew) ==
__global__ __launch_bounds__(256, 4) void i2s_gemm(
    const float* __restrict__ x, const float* __restrict__ W2g,
    const float* __restrict__ b2, const float* __restrict__ b1,
    float* __restrict__ i2s)
{
    const int tid = threadIdx.x;
    const int bx  = blockIdx.x;
    const int b   = bx >> 7;
    const int row = bx & 127;

    __shared__ __attribute__((aligned(16))) float xs[CIN][WW];
    __shared__ __attribute__((aligned(16))) float w2s[CIN][OCH];
    __shared__ float bs[OCH];

    for (int i = tid; i < CIN * OCH; i += 256) {
        const int c = i >> 7, o = i & 127;
        w2s[c][o] = W2g[o * CIN + c];
    }
    if (tid < OCH) bs[tid] = b2[tid] + b1[tid];
    for (int i = tid; i < CIN * WW; i += 256) {
        const int c = i >> 7, t = i & 127;
        xs[c][t] = (t >= row)
            ? x[((size_t)(b * CIN + c) * HH + row) * WW + (t - row)] : 0.f;
    }
    __syncthreads();

    const int tm = tid >> 4;
    const int tn = tid & 15;
    const int t0 = tm * 8, o0 = tn * 8;

    float bv[8];
    *(float4*)&bv[0] = *(const float4*)&bs[o0];
    *(float4*)&bv[4] = *(const float4*)&bs[o0 + 4];
    float acc[8][8];
#pragma unroll
    for (int i = 0; i < 8; ++i)
#pragma unroll
        for (int jj = 0; jj < 8; ++jj) acc[i][jj] = bv[jj];

    for (int c = 0; c < CIN; ++c) {
        float a[8], wv[8];
        *(float4*)&a[0]  = *(const float4*)&xs[c][t0];
        *(float4*)&a[4]  = *(const float4*)&xs[c][t0 + 4];
        *(float4*)&wv[0] = *(const float4*)&w2s[c][o0];
        *(float4*)&wv[4] = *(const float4*)&w2s[c][o0 + 4];
#pragma unroll
        for (int i = 0; i < 8; ++i)
#pragma unroll
            for (int jj = 0; jj < 8; ++jj)
                acc[i][jj] = fmaf(a[i], wv[jj], acc[i][jj]);
    }

    float* dst = i2s + (size_t)(b * HH + row) * WW * OCH;
#pragma unroll
    for (int i = 0; i < 8; ++i) {
        *(float4*)&dst[(size_t)(t0 + i) * OCH + o0]     = *(float4*)&acc[i][0];
        *(float4*)&dst[(size_t)(t0 + i) * OCH + o0 + 4] = *(float4*)&acc[i][4];
    }
}

// ===== K2: scan v9 — weights in LDS, 8-lane broadcast groups, no VGPR fight.
// Wave w owns channels w*8+(l>>3); lane row = l&7. Weight reads: 8 distinct
// 16B addrs/wave (stride 272B -> banks 0,4,..28), each broadcast to 8 lanes:
// conflict-free, 32KB/step/CU of LDS traffic vs R6-R8's 256KB/step scratch/L2.
__global__ __launch_bounds__(1024) void diag_lstm_scan_v9(
    const float* __restrict__ W1g, float* __restrict__ out,
    int* __restrict__ progress, unsigned long long* __restrict__ hand,
    const float* __restrict__ i2s)
{
    const int tid = threadIdx.x;
    const int l   = tid & 63;
    const int w   = tid >> 6;          // wave 0..15
    const int r   = l & 7;             // gate row (0..7)
    const int cw  = w * 8 + (l >> 3);  // gate channel (0..127)
    const int blk = blockIdx.x;
    const int b = (blk & 7) + ((blk >> 7) << 3);   // XCD-affinity remap
    const int k = (blk >> 3) & (NCH - 1);
    const int row = k * 8 + r;

    __shared__ __attribute__((aligned(16))) float wl[OCH][WLP];   // packed p/c
    __shared__ __attribute__((aligned(16))) float phs[2][9][PHP];
    __shared__ __attribute__((aligned(16))) float gbuf[8][GBP];

    // stage weights: wl[o][2c]=W1_prev[o][c], wl[o][2c+1]=W1_cur[o][c]
    for (int i = tid; i < OCH * CIN; i += 1024) {
        const int o = i >> 5, c = i & 31;
        const float2 wv = *(const float2*)&W1g[((size_t)o * CIN + c) * 2];
        wl[o][2 * c]     = wv.x;
        wl[o][2 * c + 1] = wv.y;
    }
    for (int i = tid; i < 2 * 9 * PHP; i += 1024) ((float*)phs)[i] = 0.f;

    // cell role: even waves, lanes < 32
    const int rc = w >> 1;
    const int j  = l & 31;
    const bool cellactive = ((w & 1) == 0) && (l < 32);
    float pc = 0.f, ob0 = 0.f, ob1 = 0.f, ob2 = 0.f;
    float* outrow = out + ((size_t)(b * BO + j) * HH + (k * 8 + rc)) * WW;

    const float* myi2s = i2s + ((size_t)(b * HH + row) * WW) * OCH + cw;

    const int kprev = (k > 0) ? k - 1 : 0;
    const unsigned long long* srcbase =
        hand + (size_t)((b * NCH + kprev) * DEPTH) * BO + j;
    unsigned long long* dstbase =
        hand + (size_t)((b * NCH + k) * DEPTH) * BO + j;
    int* myprog   = progress + (b * NCH + k);
    int* consprog = myprog + 1;

    unsigned long long pre = 0ull;
    float ip0 = myi2s[0];
    float ip1 = myi2s[(size_t)1 * OCH];

    __syncthreads();

    for (int t = 0; t < WW; ++t) {
        const int par = t & 1;

        // ---- boundary poll: EVERY wave, idempotent same-value LDS write ----
        if (k > 0 && t > 0) {
            unsigned long long q = pre;
            while (__any((unsigned)(q >> 32) != (unsigned)t)) {
                q = __hip_atomic_load(&srcbase[(size_t)((t - 1) & (DEPTH - 1)) * BO],
                                      __ATOMIC_RELAXED, __HIP_MEMORY_SCOPE_AGENT);
            }
            if (l < 32) phs[par][0][l] = __uint_as_float((unsigned)q);
            pre = __hip_atomic_load(&srcbase[(size_t)(t & (DEPTH - 1)) * BO],
                                    __ATOMIC_RELAXED, __HIP_MEMORY_SCOPE_AGENT);
            asm volatile("s_waitcnt lgkmcnt(0)" ::: "memory");
        }

        // ---- gates: 1 (row,channel)/lane; weights broadcast from LDS ----
        float g = ip0;
        ip0 = ip1;
        {
            const int tn2 = (t + 2 < WW) ? t + 2 : WW - 1;
            ip1 = myi2s[(size_t)tn2 * OCH];
        }
        {
            const float4* wrow = (const float4*)&wl[cw][0];
            const float4* prow = (const float4*)&phs[par][r][0];      // h(row-1)
            const float4* qrow = (const float4*)&phs[par][r + 1][0];  // h(row)
#pragma unroll
            for (int cc = 0; cc < 8; ++cc) {
                const float4 pv = prow[cc];
                const float4 qv = qrow[cc];
                const float4 wa = wrow[2 * cc];
                const float4 wb = wrow[2 * cc + 1];
                g = fmaf(wa.x, pv.x, g);
                g = fmaf(wa.y, qv.x, g);
                g = fmaf(wa.z, pv.y, g);
                g = fmaf(wa.w, qv.y, g);
                g = fmaf(wb.x, pv.z, g);
                g = fmaf(wb.y, qv.z, g);
                g = fmaf(wb.z, pv.w, g);
                g = fmaf(wb.w, qv.w, g);
            }
        }
        gbuf[r][cw] = g;
        __syncthreads();   // barrier A: gates published

        // ---- cell update (even waves, lanes < 32) ----
        if (cellactive) {
            if (w == 14 && k < NCH - 1 && (t & 15) == 0 && t >= 48) {
                while (__hip_atomic_load(consprog, __ATOMIC_RELAXED,
                                         __HIP_MEMORY_SCOPE_AGENT) < t - 47) { }
            }
            const float go = gbuf[rc][j];
            const float gf = gbuf[rc][32 + j];
            const float gi = gbuf[rc][64 + j];
            const float gg = gbuf[rc][96 + j];
            const float so = 1.f / (1.f + __expf(-go));
            const float sf = 1.f / (1.f + __expf(-gf));
            const float si = 1.f / (1.f + __expf(-gi));
            const float tg = 2.f / (1.f + __expf(-2.f * gg)) - 1.f;
            const float nc = sf * pc + si * tg;
            const float th = 2.f / (1.f + __expf(-2.f * nc)) - 1.f;
            const float nh = so * th;
            pc = nc;
            phs[par ^ 1][rc + 1][j] = nh;

            const int ph4 = t & 3;
            if (ph4 == 0) ob0 = nh;
            else if (ph4 == 1) ob1 = nh;
            else if (ph4 == 2) ob2 = nh;
            else *(float4*)(outrow + (t - 3)) = make_float4(ob0, ob1, ob2, nh);

            if (w == 14 && k < NCH - 1) {   // rc==7: handoff tag t+1, slot t&63
                unsigned long long q = ((unsigned long long)(unsigned)(t + 1) << 32)
                                     | (unsigned long long)__float_as_uint(nh);
                __hip_atomic_store(&dstbase[(size_t)(t & (DEPTH - 1)) * BO], q,
                                   __ATOMIC_RELAXED, __HIP_MEMORY_SCOPE_AGENT);
            }
            if (w == 0 && l == 0) {
                __hip_atomic_store(myprog, t + 1, __ATOMIC_RELAXED,
                                   __HIP_MEMORY_SCOPE_AGENT);
            }
        }
        __syncthreads();   // barrier B: phs[par^1] published
    }
}

// ===================== fallback (R4, proven, ws-lean) =====================
__global__ __launch_bounds__(512, 2) void diag_lstm_scan_v4(
    const float* __restrict__ x, const float* __restrict__ W2g,
    const float* __restrict__ b2, const float* __restrict__ W1g,
    const float* __restrict__ b1, float* __restrict__ out,
    int* __restrict__ progress, unsigned long long* __restrict__ hand)
{
    const int tid = threadIdx.x;
    const int l   = tid & 63;
    const int w   = tid >> 6;
    const int blk = blockIdx.x;
    const int b = (blk & 7) + ((blk >> 7) << 3);
    const int k = (blk >> 3) & (NCH - 1);
    const int row = k * 8 + w;

    __shared__ __attribute__((aligned(16))) float phs[2][9][BO];
    __shared__ __attribute__((aligned(16))) float xbuf[8][CIN];
    __shared__ __attribute__((aligned(16))) float gbuf[8][OCH];

    for (int i = tid; i < 2 * 9 * BO; i += 512) ((float*)phs)[i] = 0.f;

    const int o0 = 2 * l, o1 = 2 * l + 1;
    float w2a[CIN], w2b[CIN], w1pa[CIN], w1ca[CIN], w1pb[CIN], w1cb[CIN];
#pragma unroll
    for (int c = 0; c < CIN; ++c) {
        w2a[c]  = W2g[o0 * CIN + c];
        w2b[c]  = W2g[o1 * CIN + c];
        w1pa[c] = W1g[(o0 * CIN + c) * 2 + 0];
        w1ca[c] = W1g[(o0 * CIN + c) * 2 + 1];
        w1pb[c] = W1g[(o1 * CIN + c) * 2 + 0];
        w1cb[c] = W1g[(o1 * CIN + c) * 2 + 1];
    }
    const float biasA = b2[o0] + b1[o0];
    const float biasB = b2[o1] + b1[o1];

    const int j = l & 31;
    float pc = 0.f, ob0 = 0.f, ob1 = 0.f, ob2 = 0.f;
    float* outrow = out + ((size_t)(b * BO + j) * HH + row) * WW;

    const int kprev = (k > 0) ? k - 1 : 0;
    const unsigned long long* srcbase =
        hand + (size_t)((b * NCH + kprev) * DEPTH) * BO + j;
    unsigned long long* dstbase =
        hand + (size_t)((b * NCH + k) * DEPTH) * BO + j;
    int* myprog   = progress + (b * NCH + k);
    int* consprog = myprog + 1;

    unsigned long long pre = 0ull;
    __syncthreads();

    for (int t = 0; t < WW; ++t) {
        const int par = t & 1;
        if (l < 32) {
            const int wp = t - row;
            xbuf[w][l] = (wp >= 0)
                ? x[((size_t)(b * CIN + l) * HH + row) * WW + wp] : 0.f;
        }
        if (w == 0 && k > 0) {
            if (t > 0) {
                unsigned long long q = pre;
                while (__any((unsigned)(q >> 32) != (unsigned)t)) {
                    q = __hip_atomic_load(&srcbase[(size_t)((t - 1) & (DEPTH - 1)) * BO],
                                          __ATOMIC_RELAXED, __HIP_MEMORY_SCOPE_AGENT);
                }
                if (l < 32) phs[par][0][l] = __uint_as_float((unsigned)q);
            }
            pre = __hip_atomic_load(&srcbase[(size_t)(t & (DEPTH - 1)) * BO],
                                    __ATOMIC_RELAXED, __HIP_MEMORY_SCOPE_AGENT);
        }
        asm volatile("s_waitcnt lgkmcnt(0)" ::: "memory");

        float ga = biasA, gb = biasB;
        {
            const float4* xb4 = (const float4*)(&xbuf[w][0]);
            const float4* pv4 = (const float4*)(&phs[par][w][0]);
            const float4* qv4 = (const float4*)(&phs[par][w + 1][0]);
#pragma unroll
            for (int cc = 0; cc < CIN / 4; ++cc) {
                const float4 xv = xb4[cc];
                const float4 pv = pv4[cc];
                const float4 qv = qv4[cc];
                const float* xs = (const float*)&xv;
                const float* ps = (const float*)&pv;
                const float* qs = (const float*)&qv;
#pragma unroll
                for (int ci = 0; ci < 4; ++ci) {
                    const int c = 4 * cc + ci;
                    ga = fmaf(w2a[c],  xs[ci], ga);
                    gb = fmaf(w2b[c],  xs[ci], gb);
                    ga = fmaf(w1pa[c], ps[ci], ga);
                    gb = fmaf(w1pb[c], ps[ci], gb);
                    ga = fmaf(w1ca[c], qs[ci], ga);
                    gb = fmaf(w1cb[c], qs[ci], gb);
                }
            }
        }
        *(float2*)&gbuf[w][o0] = make_float2(ga, gb);
        asm volatile("s_waitcnt lgkmcnt(0)" ::: "memory");

        if (l < 32) {
            if (w == 7 && k < NCH - 1 && (t & 15) == 0 && t >= 48) {
                while (__hip_atomic_load(consprog, __ATOMIC_RELAXED,
                                         __HIP_MEMORY_SCOPE_AGENT) < t - 47) { }
            }
            const float go = gbuf[w][l];
            const float gf = gbuf[w][32 + l];
            const float gi = gbuf[w][64 + l];
            const float gg = gbuf[w][96 + l];
            const float so = 1.f / (1.f + __expf(-go));
            const float sf = 1.f / (1.f + __expf(-gf));
            const float si = 1.f / (1.f + __expf(-gi));
            const float tg = 2.f / (1.f + __expf(-2.f * gg)) - 1.f;
            const float nc = sf * pc + si * tg;
            const float th = 2.f / (1.f + __expf(-2.f * nc)) - 1.f;
            const float nh = so * th;
            pc = nc;
            phs[par ^ 1][w + 1][l] = nh;

            const int ph4 = t & 3;
            if (ph4 == 0) ob0 = nh;
            else if (ph4 == 1) ob1 = nh;
            else if (ph4 == 2) ob2 = nh;
            else *(float4*)(outrow + (t - 3)) = make_float4(ob0, ob1, ob2, nh);

            if (w == 7 && k < NCH - 1) {
                unsigned long long q = ((unsigned long long)(unsigned)(t + 1) << 32)
                                     | (unsigned long long)__float_as_uint(nh);
                __hip_atomic_store(&dstbase[(size_t)(t & (DEPTH - 1)) * BO], q,
                                   __ATOMIC_RELAXED, __HIP_MEMORY_SCOPE_AGENT);
            }
            if (w == 0 && l == 0) {
                __hip_atomic_store(myprog, t + 1, __ATOMIC_RELAXED,
                                   __HIP_MEMORY_SCOPE_AGENT);
            }
        }
        __syncthreads();
    }
}

extern "C" void kernel_launch(void* const* d_in, const int* in_sizes, int n_in,
                              void* d_out, int out_size, void* d_ws, size_t ws_size,
                              hipStream_t stream) {
    const float* x  = (const float*)d_in[0];
    const float* W2 = (const float*)d_in[1];
    const float* b2 = (const float*)d_in[2];
    const float* W1 = (const float*)d_in[3];
    const float* b1 = (const float*)d_in[4];
    float* out = (float*)d_out;

    int* progress = (int*)d_ws;
    unsigned long long* hand = (unsigned long long*)((char*)d_ws + 4096);
    float* i2s = (float*)((char*)d_ws + 4096 + RINGSZ);

    const size_t need = 4096 + RINGSZ + I2SSZ;

    hipMemsetAsync(d_ws, 0, 4096 + RINGSZ, stream);

    if (ws_size >= need) {
        hipLaunchKernelGGL(i2s_gemm, dim3(BATCH * HH), dim3(256), 0, stream,
                           x, W2, b2, b1, i2s);
        hipLaunchKernelGGL(diag_lstm_scan_v9, dim3(BATCH * NCH), dim3(1024), 0, stream,
                           W1, out, progress, hand, i2s);
    } else {
        hipLaunchKernelGGL(diag_lstm_scan_v4, dim3(BATCH * NCH), dim3(512), 0, stream,
                           x, W2, b2, W1, b1, out, progress, hand);
    }
}

// Round 10
// 209.784 us; speedup vs baseline: 1.7888x; 1.7888x over previous
//
#include <hip/hip_runtime.h>
#include <stdint.h>

#define BATCH 16
#define CIN   32
#define HH    128
#define WW    128
#define BO    32
#define OCH   128   // 4*BO
#define NCH   16    // h-chunks (8 rows each)
#define DEPTH 64    // handoff ring depth (power of 2)

#define PHP   40    // padded phs row: stride 40 words -> A-build reads <=2-way
#define GBP   132   // padded gbuf row

// ws: [0,4096) progress ints
//     [4096, +RINGSZ) tagged handoff ring
//     [4096+RINGSZ, +I2SHSZ) i2s buffer (f16, layout [b][t][row][o])
#define RINGSZ ((size_t)BATCH * NCH * DEPTH * BO * 8)
#define I2SHSZ ((size_t)BATCH * WW * HH * OCH * 2)

typedef _Float16 f16x8 __attribute__((ext_vector_type(8)));
typedef float    f32x4 __attribute__((ext_vector_type(4)));

// ===== K1: i2s_h[b][t][row][o] = (f16)(b2+b1 + sum_c W2[o][c]*xskew) ========
__global__ __launch_bounds__(256, 4) void i2s_gemm_h(
    const float* __restrict__ x, const float* __restrict__ W2g,
    const float* __restrict__ b2, const float* __restrict__ b1,
    _Float16* __restrict__ i2sh)
{
    const int tid = threadIdx.x;
    const int bx  = blockIdx.x;
    const int b   = bx >> 7;
    const int row = bx & 127;

    __shared__ __attribute__((aligned(16))) float xs[CIN][WW];
    __shared__ __attribute__((aligned(16))) float w2s[CIN][OCH];
    __shared__ float bs[OCH];

    for (int i = tid; i < CIN * OCH; i += 256) {
        const int c = i >> 7, o = i & 127;
        w2s[c][o] = W2g[o * CIN + c];
    }
    if (tid < OCH) bs[tid] = b2[tid] + b1[tid];
    for (int i = tid; i < CIN * WW; i += 256) {
        const int c = i >> 7, t = i & 127;
        xs[c][t] = (t >= row)
            ? x[((size_t)(b * CIN + c) * HH + row) * WW + (t - row)] : 0.f;
    }
    __syncthreads();

    const int tm = tid >> 4;
    const int tn = tid & 15;
    const int t0 = tm * 8, o0 = tn * 8;

    float bv[8];
    *(float4*)&bv[0] = *(const float4*)&bs[o0];
    *(float4*)&bv[4] = *(const float4*)&bs[o0 + 4];
    float acc[8][8];
#pragma unroll
    for (int i = 0; i < 8; ++i)
#pragma unroll
        for (int jj = 0; jj < 8; ++jj) acc[i][jj] = bv[jj];

    for (int c = 0; c < CIN; ++c) {
        float a[8], wv[8];
        *(float4*)&a[0]  = *(const float4*)&xs[c][t0];
        *(float4*)&a[4]  = *(const float4*)&xs[c][t0 + 4];
        *(float4*)&wv[0] = *(const float4*)&w2s[c][o0];
        *(float4*)&wv[4] = *(const float4*)&w2s[c][o0 + 4];
#pragma unroll
        for (int i = 0; i < 8; ++i)
#pragma unroll
            for (int jj = 0; jj < 8; ++jj)
                acc[i][jj] = fmaf(a[i], wv[jj], acc[i][jj]);
    }

#pragma unroll
    for (int i = 0; i < 8; ++i) {
        f16x8 hv;
#pragma unroll
        for (int jj = 0; jj < 8; ++jj) hv[jj] = (_Float16)acc[i][jj];
        *(f16x8*)&i2sh[((size_t)(b * WW + (t0 + i)) * HH + row) * OCH + o0] = hv;
    }
}

// ===== K2: scan v10 — recurrent GEMM via MFMA f16; W1 lives in 8 B-frag
// VGPRs/lane loaded ONCE (kills the 4500cyc/step weight-rereads of R6-R9).
// 8 waves; wave wv owns channels 16wv..16wv+15 (one 16x16x32 N-tile, K=64 ->
// 2 chained MFMAs). A (8x64) built per step from phs: A[m][2c]=h[m-1][c],
// A[m][2c+1]=h[m][c]. Layouts: A: m=l&15,k=(l>>4)*8+e; B: n=l&15,same k;
// D: col=l&15,row=(l>>4)*4+e (m89/m201-verified convention).
__global__ __launch_bounds__(512) void diag_lstm_scan_v10(
    const float* __restrict__ W1g, float* __restrict__ out,
    int* __restrict__ progress, unsigned long long* __restrict__ hand,
    const _Float16* __restrict__ i2sh)
{
    const int tid = threadIdx.x;
    const int l   = tid & 63;
    const int wv  = tid >> 6;          // wave 0..7
    const int blk = blockIdx.x;
    const int b = (blk & 7) + ((blk >> 7) << 3);   // XCD-affinity remap
    const int k = (blk >> 3) & (NCH - 1);

    __shared__ __attribute__((aligned(16))) float    phs[2][9][PHP];
    __shared__ __attribute__((aligned(16))) float    gbuf[8][GBP];
    __shared__ __attribute__((aligned(16))) _Float16 ibuf[2][8][OCH];

    for (int i = tid; i < 2 * 9 * PHP; i += 512) ((float*)phs)[i] = 0.f;

    // ---- B-frags: W[o][k] = W1g[o*64 + k] (k=2c+which), loaded once ----
    const int n  = l & 15;
    const int kq = l >> 4;
    const int o  = wv * 16 + n;
    f16x8 bw0, bw1;
    {
        const float4 a0 = *(const float4*)&W1g[(size_t)o * 64 + 8 * kq];
        const float4 a1 = *(const float4*)&W1g[(size_t)o * 64 + 8 * kq + 4];
        const float4 c0 = *(const float4*)&W1g[(size_t)o * 64 + 32 + 8 * kq];
        const float4 c1 = *(const float4*)&W1g[(size_t)o * 64 + 32 + 8 * kq + 4];
        bw0[0] = (_Float16)a0.x; bw0[1] = (_Float16)a0.y;
        bw0[2] = (_Float16)a0.z; bw0[3] = (_Float16)a0.w;
        bw0[4] = (_Float16)a1.x; bw0[5] = (_Float16)a1.y;
        bw0[6] = (_Float16)a1.z; bw0[7] = (_Float16)a1.w;
        bw1[0] = (_Float16)c0.x; bw1[1] = (_Float16)c0.y;
        bw1[2] = (_Float16)c0.z; bw1[3] = (_Float16)c0.w;
        bw1[4] = (_Float16)c1.x; bw1[5] = (_Float16)c1.y;
        bw1[6] = (_Float16)c1.z; bw1[7] = (_Float16)c1.w;
    }

    // ---- cell role (waves 0..3): row r = 2wv + (l>>5), channel j = l&31 ----
    const int r = (2 * wv + (l >> 5)) & 7;
    const int j = l & 31;
    float pc = 0.f, ob0 = 0.f, ob1 = 0.f, ob2 = 0.f;
    float* outrow = out + ((size_t)(b * BO + j) * HH + (k * 8 + r)) * WW;

    // ---- ring handoff ----
    const int kprev = (k > 0) ? k - 1 : 0;
    const unsigned long long* srcbase =
        hand + (size_t)((b * NCH + kprev) * DEPTH) * BO + j;
    unsigned long long* dstbase =
        hand + (size_t)((b * NCH + k) * DEPTH) * BO + j;
    int* myprog   = progress + (b * NCH + k);
    int* consprog = myprog + 1;
    unsigned long long pre = 0ull;

    // ---- i2s prefetch: [b][t][row][o] f16; block slice = 8 rows = 2KB/t ----
    const size_t islab = (size_t)HH * OCH;  // halfs per t
    const _Float16* ibase0 = i2sh + ((size_t)(b * WW) * HH + k * 8) * OCH;
    const int ii = tid & 255;               // staging index for waves 4..7
    uint2 pr0 = make_uint2(0, 0), pr1 = make_uint2(0, 0);

    ((unsigned int*)&ibuf[0][0][0])[tid] = ((const unsigned int*)ibase0)[tid]; // t=0
    if (wv >= 4) {
        pr0 = ((const uint2*)(ibase0 + 1 * islab))[ii];   // t=1
        pr1 = ((const uint2*)(ibase0 + 2 * islab))[ii];   // t=2
    }
    __syncthreads();

    for (int t = 0; t < WW; ++t) {
        const int par = t & 1;

        // ---- boundary poll (all waves, idempotent writes) ----
        if (k > 0 && t > 0) {
            unsigned long long q = pre;
            while (__any((unsigned)(q >> 32) != (unsigned)t)) {
                q = __hip_atomic_load(&srcbase[(size_t)((t - 1) & (DEPTH - 1)) * BO],
                                      __ATOMIC_RELAXED, __HIP_MEMORY_SCOPE_AGENT);
            }
            if (l < 32) phs[par][0][l] = __uint_as_float((unsigned)q);
            pre = __hip_atomic_load(&srcbase[(size_t)(t & (DEPTH - 1)) * BO],
                                    __ATOMIC_RELAXED, __HIP_MEMORY_SCOPE_AGENT);
            asm volatile("s_waitcnt lgkmcnt(0)" ::: "memory");
        }

        // ---- A-frags from phs (m = n = l&15; rows >= 8 are zero padding) ----
        f16x8 af0 = {}; f16x8 af1 = {};
        if (n < 8) {
            const float4 P0 = *(const float4*)&phs[par][n    ][4 * kq];
            const float4 Q0 = *(const float4*)&phs[par][n + 1][4 * kq];
            const float4 P1 = *(const float4*)&phs[par][n    ][16 + 4 * kq];
            const float4 Q1 = *(const float4*)&phs[par][n + 1][16 + 4 * kq];
            af0[0] = (_Float16)P0.x; af0[1] = (_Float16)Q0.x;
            af0[2] = (_Float16)P0.y; af0[3] = (_Float16)Q0.y;
            af0[4] = (_Float16)P0.z; af0[5] = (_Float16)Q0.z;
            af0[6] = (_Float16)P0.w; af0[7] = (_Float16)Q0.w;
            af1[0] = (_Float16)P1.x; af1[1] = (_Float16)Q1.x;
            af1[2] = (_Float16)P1.y; af1[3] = (_Float16)Q1.y;
            af1[4] = (_Float16)P1.z; af1[5] = (_Float16)Q1.z;
            af1[6] = (_Float16)P1.w; af1[7] = (_Float16)Q1.w;
        }

        f32x4 acc = {0.f, 0.f, 0.f, 0.f};
        acc = __builtin_amdgcn_mfma_f32_16x16x32_f16(af0, bw0, acc, 0, 0, 0);
        acc = __builtin_amdgcn_mfma_f32_16x16x32_f16(af1, bw1, acc, 0, 0, 0);

        // ---- gate write: lane l<32 holds rows 4*kq+e, col n ----
        if (l < 32) {
#pragma unroll
            for (int e = 0; e < 4; ++e)
                gbuf[4 * kq + e][wv * 16 + n] = acc[e];
        }

        // ---- waves 4..7: stage i2s for t+1, issue load for t+3 ----
        if (wv >= 4) {
            ((uint2*)&ibuf[(t + 1) & 1][0][0])[ii] = pr0;
            pr0 = pr1;
            const int t3 = (t + 3 < WW) ? t + 3 : WW - 1;
            pr1 = ((const uint2*)(ibase0 + (size_t)t3 * islab))[ii];
        }
        __syncthreads();   // barrier A: gates + ibuf staged

        // ---- cell update (waves 0..3) ----
        if (wv < 4) {
            if (wv == 3 && l >= 32 && k < NCH - 1 && (t & 15) == 0 && t >= 48) {
                while (__hip_atomic_load(consprog, __ATOMIC_RELAXED,
                                         __HIP_MEMORY_SCOPE_AGENT) < t - 47) { }
            }
            const float go = gbuf[r][j]      + (float)ibuf[par][r][j];
            const float gf = gbuf[r][32 + j] + (float)ibuf[par][r][32 + j];
            const float gi = gbuf[r][64 + j] + (float)ibuf[par][r][64 + j];
            const float gg = gbuf[r][96 + j] + (float)ibuf[par][r][96 + j];
            const float so = 1.f / (1.f + __expf(-go));
            const float sf = 1.f / (1.f + __expf(-gf));
            const float si = 1.f / (1.f + __expf(-gi));
            const float tg = 2.f / (1.f + __expf(-2.f * gg)) - 1.f;
            const float nc = sf * pc + si * tg;
            const float th = 2.f / (1.f + __expf(-2.f * nc)) - 1.f;
            const float nh = so * th;
            pc = nc;
            phs[par ^ 1][r + 1][j] = nh;

            const int ph4 = t & 3;
            if (ph4 == 0) ob0 = nh;
            else if (ph4 == 1) ob1 = nh;
            else if (ph4 == 2) ob2 = nh;
            else *(float4*)(outrow + (t - 3)) = make_float4(ob0, ob1, ob2, nh);

            if (wv == 3 && l >= 32 && k < NCH - 1) {   // r==7: handoff
                unsigned long long q = ((unsigned long long)(unsigned)(t + 1) << 32)
                                     | (unsigned long long)__float_as_uint(nh);
                __hip_atomic_store(&dstbase[(size_t)(t & (DEPTH - 1)) * BO], q,
                                   __ATOMIC_RELAXED, __HIP_MEMORY_SCOPE_AGENT);
            }
            if (tid == 0) {
                __hip_atomic_store(myprog, t + 1, __ATOMIC_RELAXED,
                                   __HIP_MEMORY_SCOPE_AGENT);
            }
        }
        __syncthreads();   // barrier B: phs[par^1] published
    }
}

// ===================== fallback (R4, proven, ws-lean) =====================
__global__ __launch_bounds__(512, 2) void diag_lstm_scan_v4(
    const float* __restrict__ x, const float* __restrict__ W2g,
    const float* __restrict__ b2, const float* __restrict__ W1g,
    const float* __restrict__ b1, float* __restrict__ out,
    int* __restrict__ progress, unsigned long long* __restrict__ hand)
{
    const int tid = threadIdx.x;
    const int l   = tid & 63;
    const int w   = tid >> 6;
    const int blk = blockIdx.x;
    const int b = (blk & 7) + ((blk >> 7) << 3);
    const int k = (blk >> 3) & (NCH - 1);
    const int row = k * 8 + w;

    __shared__ __attribute__((aligned(16))) float phs[2][9][BO];
    __shared__ __attribute__((aligned(16))) float xbuf[8][CIN];
    __shared__ __attribute__((aligned(16))) float gbuf2[8][OCH];

    for (int i = tid; i < 2 * 9 * BO; i += 512) ((float*)phs)[i] = 0.f;

    const int o0 = 2 * l, o1 = 2 * l + 1;
    float w2a[CIN], w2b[CIN], w1pa[CIN], w1ca[CIN], w1pb[CIN], w1cb[CIN];
#pragma unroll
    for (int c = 0; c < CIN; ++c) {
        w2a[c]  = W2g[o0 * CIN + c];
        w2b[c]  = W2g[o1 * CIN + c];
        w1pa[c] = W1g[(o0 * CIN + c) * 2 + 0];
        w1ca[c] = W1g[(o0 * CIN + c) * 2 + 1];
        w1pb[c] = W1g[(o1 * CIN + c) * 2 + 0];
        w1cb[c] = W1g[(o1 * CIN + c) * 2 + 1];
    }
    const float biasA = b2[o0] + b1[o0];
    const float biasB = b2[o1] + b1[o1];

    const int j = l & 31;
    float pc = 0.f, ob0 = 0.f, ob1 = 0.f, ob2 = 0.f;
    float* outrow = out + ((size_t)(b * BO + j) * HH + row) * WW;

    const int kprev = (k > 0) ? k - 1 : 0;
    const unsigned long long* srcbase =
        hand + (size_t)((b * NCH + kprev) * DEPTH) * BO + j;
    unsigned long long* dstbase =
        hand + (size_t)((b * NCH + k) * DEPTH) * BO + j;
    int* myprog   = progress + (b * NCH + k);
    int* consprog = myprog + 1;

    unsigned long long pre = 0ull;
    __syncthreads();

    for (int t = 0; t < WW; ++t) {
        const int par = t & 1;
        if (l < 32) {
            const int wp = t - row;
            xbuf[w][l] = (wp >= 0)
                ? x[((size_t)(b * CIN + l) * HH + row) * WW + wp] : 0.f;
        }
        if (w == 0 && k > 0) {
            if (t > 0) {
                unsigned long long q = pre;
                while (__any((unsigned)(q >> 32) != (unsigned)t)) {
                    q = __hip_atomic_load(&srcbase[(size_t)((t - 1) & (DEPTH - 1)) * BO],
                                          __ATOMIC_RELAXED, __HIP_MEMORY_SCOPE_AGENT);
                }
                if (l < 32) phs[par][0][l] = __uint_as_float((unsigned)q);
            }
            pre = __hip_atomic_load(&srcbase[(size_t)(t & (DEPTH - 1)) * BO],
                                    __ATOMIC_RELAXED, __HIP_MEMORY_SCOPE_AGENT);
        }
        asm volatile("s_waitcnt lgkmcnt(0)" ::: "memory");

        float ga = biasA, gb = biasB;
        {
            const float4* xb4 = (const float4*)(&xbuf[w][0]);
            const float4* pv4 = (const float4*)(&phs[par][w][0]);
            const float4* qv4 = (const float4*)(&phs[par][w + 1][0]);
#pragma unroll
            for (int cc = 0; cc < CIN / 4; ++cc) {
                const float4 xv = xb4[cc];
                const float4 pv = pv4[cc];
                const float4 qv = qv4[cc];
                const float* xs = (const float*)&xv;
                const float* ps = (const float*)&pv;
                const float* qs = (const float*)&qv;
#pragma unroll
                for (int ci = 0; ci < 4; ++ci) {
                    const int c = 4 * cc + ci;
                    ga = fmaf(w2a[c],  xs[ci], ga);
                    gb = fmaf(w2b[c],  xs[ci], gb);
                    ga = fmaf(w1pa[c], ps[ci], ga);
                    gb = fmaf(w1pb[c], ps[ci], gb);
                    ga = fmaf(w1ca[c], qs[ci], ga);
                    gb = fmaf(w1cb[c], qs[ci], gb);
                }
            }
        }
        *(float2*)&gbuf2[w][o0] = make_float2(ga, gb);
        asm volatile("s_waitcnt lgkmcnt(0)" ::: "memory");

        if (l < 32) {
            if (w == 7 && k < NCH - 1 && (t & 15) == 0 && t >= 48) {
                while (__hip_atomic_load(consprog, __ATOMIC_RELAXED,
                                         __HIP_MEMORY_SCOPE_AGENT) < t - 47) { }
            }
            const float go = gbuf2[w][l];
            const float gf = gbuf2[w][32 + l];
            const float gi = gbuf2[w][64 + l];
            const float gg = gbuf2[w][96 + l];
            const float so = 1.f / (1.f + __expf(-go));
            const float sf = 1.f / (1.f + __expf(-gf));
            const float si = 1.f / (1.f + __expf(-gi));
            const float tg = 2.f / (1.f + __expf(-2.f * gg)) - 1.f;
            const float nc = sf * pc + si * tg;
            const float th = 2.f / (1.f + __expf(-2.f * nc)) - 1.f;
            const float nh = so * th;
            pc = nc;
            phs[par ^ 1][w + 1][l] = nh;

            const int ph4 = t & 3;
            if (ph4 == 0) ob0 = nh;
            else if (ph4 == 1) ob1 = nh;
            else if (ph4 == 2) ob2 = nh;
            else *(float4*)(outrow + (t - 3)) = make_float4(ob0, ob1, ob2, nh);

            if (w == 7 && k < NCH - 1) {
                unsigned long long q = ((unsigned long long)(unsigned)(t + 1) << 32)
                                     | (unsigned long long)__float_as_uint(nh);
                __hip_atomic_store(&dstbase[(size_t)(t & (DEPTH - 1)) * BO], q,
                                   __ATOMIC_RELAXED, __HIP_MEMORY_SCOPE_AGENT);
            }
            if (w == 0 && l == 0) {
                __hip_atomic_store(myprog, t + 1, __ATOMIC_RELAXED,
                                   __HIP_MEMORY_SCOPE_AGENT);
            }
        }
        __syncthreads();
    }
}

extern "C" void kernel_launch(void* const* d_in, const int* in_sizes, int n_in,
                              void* d_out, int out_size, void* d_ws, size_t ws_size,
                              hipStream_t stream) {
    const float* x  = (const float*)d_in[0];
    const float* W2 = (const float*)d_in[1];
    const float* b2 = (const float*)d_in[2];
    const float* W1 = (const float*)d_in[3];
    const float* b1 = (const float*)d_in[4];
    float* out = (float*)d_out;

    int* progress = (int*)d_ws;
    unsigned long long* hand = (unsigned long long*)((char*)d_ws + 4096);
    _Float16* i2sh = (_Float16*)((char*)d_ws + 4096 + RINGSZ);

    const size_t need = 4096 + RINGSZ + I2SHSZ;

    hipMemsetAsync(d_ws, 0, 4096 + RINGSZ, stream);

    if (ws_size >= need) {
        hipLaunchKernelGGL(i2s_gemm_h, dim3(BATCH * HH), dim3(256), 0, stream,
                           x, W2, b2, b1, i2sh);
        hipLaunchKernelGGL(diag_lstm_scan_v10, dim3(BATCH * NCH), dim3(512), 0, stream,
                           W1, out, progress, hand, i2sh);
    } else {
        hipLaunchKernelGGL(diag_lstm_scan_v4, dim3(BATCH * NCH), dim3(512), 0, stream,
                           x, W2, b2, W1, b1, out, progress, hand);
    }
}